// Round 1
// baseline (3038.102 us; speedup 1.0000x reference)
//
#include <hip/hip_runtime.h>
#include <stdint.h>

#define HDIM  4096
#define VOCAB 32000
#define BT    4096
#define IGN   (-100)

typedef __attribute__((ext_vector_type(8))) short short8;
typedef __attribute__((ext_vector_type(4))) float f32x4;

// ---------------- f32 -> bf16 (RNE), header-free ----------------
__device__ __forceinline__ unsigned short f2bf(float x) {
  unsigned int u = __builtin_bit_cast(unsigned int, x);
  u += 0x7fffu + ((u >> 16) & 1u);
  return (unsigned short)(u >> 16);
}

__global__ void cvt_kernel(const float* __restrict__ in, unsigned short* __restrict__ out, int n4) {
  int idx = blockIdx.x * blockDim.x + threadIdx.x;
  int stride = gridDim.x * blockDim.x;
  const float4* in4 = (const float4*)in;
  ushort4* out4 = (ushort4*)out;
  for (int i = idx; i < n4; i += stride) {
    float4 v = in4[i];
    ushort4 o;
    o.x = f2bf(v.x); o.y = f2bf(v.y); o.z = f2bf(v.z); o.w = f2bf(v.w);
    out4[i] = o;
  }
}

// ---------------- target logits, full f32 precision ----------------
__global__ __launch_bounds__(256) void tgt_kernel(
    const float* __restrict__ x_p, const float* __restrict__ w_p, const float* __restrict__ b_p,
    const float* __restrict__ x_r, const float* __restrict__ w_r, const float* __restrict__ b_r,
    const int* __restrict__ target, float* __restrict__ out /* [2][BT] */) {
  const int model = blockIdx.y;
  const float* x = model ? x_r : x_p;
  const float* w = model ? w_r : w_p;
  const float* b = model ? b_r : b_p;
  const int wave = threadIdx.x >> 6, lane = threadIdx.x & 63;
  const int token = blockIdx.x * 4 + wave;
  int y = target[token];
  int ys = (y < 0) ? 0 : y;
  const float4* xr = (const float4*)(x + (size_t)token * HDIM);
  const float4* wr = (const float4*)(w + (size_t)ys * HDIM);
  float acc = 0.f;
#pragma unroll
  for (int it = 0; it < 16; ++it) {
    float4 a = xr[lane + 64 * it];
    float4 bv = wr[lane + 64 * it];
    acc += a.x * bv.x + a.y * bv.y + a.z * bv.z + a.w * bv.w;
  }
#pragma unroll
  for (int m = 32; m >= 1; m >>= 1) acc += __shfl_xor(acc, m, 64);
  if (lane == 0) out[model * BT + token] = acc + b[ys];
}

// ---------------- fused GEMM + sum-exp epilogue ----------------
typedef __attribute__((address_space(1))) void gvoid_t;
typedef __attribute__((address_space(3))) void lvoid_t;
__device__ __forceinline__ void load_lds16(const void* g, void* l) {
  __builtin_amdgcn_global_load_lds((gvoid_t*)g, (lvoid_t*)l, 16, 0, 0);
}

__global__ __launch_bounds__(256, 3) void gemm_lse_kernel(
    const unsigned short* __restrict__ Xp, const unsigned short* __restrict__ Wp, const float* __restrict__ bp,
    const unsigned short* __restrict__ Xr, const unsigned short* __restrict__ Wr, const float* __restrict__ br,
    float* __restrict__ rowsum /* [2][BT] */) {
  const int model = blockIdx.y;
  const unsigned short* X = model ? Xr : Xp;
  const unsigned short* W = model ? Wr : Wp;
  const float* bias = model ? br : bp;
  float* rs = rowsum + model * BT;

  __shared__ __align__(16) unsigned short As[128 * 64];  // 16 KB
  __shared__ __align__(16) unsigned short Bs[128 * 64];  // 16 KB
  __shared__ float redbuf[2][2][64];                     // 1 KB

  const int tid = threadIdx.x;
  const int mtile = blockIdx.x & 31;   // mtile-fast: 32 row-tiles share one W col-tile in LLC
  const int ntile = blockIdx.x >> 5;
  const int row0 = mtile * 128;
  const int col0 = ntile * 128;
  const int lane = tid & 63;
  const int wave = tid >> 6;
  const int wr = wave >> 1, wc = wave & 1;
  const int q = lane >> 4;
  const int c = lane & 15;

  f32x4 acc[4][4] = {};

  // staging map: element slot e = t*2048 + tid*8 ; LDS byte = 2e = waveBase + lane*16 (required layout)
  int sm[4], sk[4], se[4];
#pragma unroll
  for (int t = 0; t < 4; ++t) {
    int e = t * 2048 + tid * 8;
    se[t] = e;
    int m = e >> 6;
    int kl = e & 63;
    sm[t] = m;
    sk[t] = kl ^ ((m & 7) << 3);  // XOR bank swizzle (applied on global side)
  }
  const unsigned short* Xb = X + (size_t)row0 * HDIM;
  const unsigned short* Wb = W + (size_t)col0 * HDIM;

  int arow[4], brow[4];
#pragma unroll
  for (int i = 0; i < 4; ++i) arow[i] = wr * 64 + i * 16 + c;
#pragma unroll
  for (int j = 0; j < 4; ++j) brow[j] = wc * 64 + j * 16 + c;
  const int ksw = (c & 7) << 3;  // read-side swizzle (row&7 == c&7 for all fragments)

  for (int kt = 0; kt < HDIM; kt += 64) {
#pragma unroll
    for (int t = 0; t < 4; ++t) {
      load_lds16(Xb + (size_t)sm[t] * HDIM + kt + sk[t], &As[se[t]]);
      load_lds16(Wb + (size_t)sm[t] * HDIM + kt + sk[t], &Bs[se[t]]);
    }
    __syncthreads();
#pragma unroll
    for (int ks = 0; ks < 64; ks += 32) {
      const int kf = ks + q * 8;
      short8 af[4], bf[4];
#pragma unroll
      for (int i = 0; i < 4; ++i) af[i] = *(const short8*)&As[arow[i] * 64 + (kf ^ ksw)];
#pragma unroll
      for (int j = 0; j < 4; ++j) bf[j] = *(const short8*)&Bs[brow[j] * 64 + (kf ^ ksw)];
#pragma unroll
      for (int i = 0; i < 4; ++i)
#pragma unroll
        for (int j = 0; j < 4; ++j)
          acc[i][j] = __builtin_amdgcn_mfma_f32_16x16x32_bf16(af[i], bf[j], acc[i][j], 0, 0, 0);
    }
    __syncthreads();
  }

  // epilogue: per-row sum of exp(logit + bias) over this 128-col tile.
  // C/D layout: row = wr*64 + i*16 + q*4 + reg ; col = wc*64 + j*16 + c
  float bb[4];
#pragma unroll
  for (int j = 0; j < 4; ++j) bb[j] = bias[col0 + wc * 64 + j * 16 + c];

#pragma unroll
  for (int i = 0; i < 4; ++i) {
#pragma unroll
    for (int reg = 0; reg < 4; ++reg) {
      float v = 0.f;
#pragma unroll
      for (int j = 0; j < 4; ++j) v += __expf(acc[i][j][reg] + bb[j]);
      v += __shfl_xor(v, 1, 64);
      v += __shfl_xor(v, 2, 64);
      v += __shfl_xor(v, 4, 64);
      v += __shfl_xor(v, 8, 64);
      if (c == 0) redbuf[wr][wc][i * 16 + q * 4 + reg] = v;
    }
  }
  __syncthreads();
  if (tid < 128) {
    float tot = redbuf[tid >> 6][0][tid & 63] + redbuf[tid >> 6][1][tid & 63];
    atomicAdd(&rs[row0 + tid], tot);
  }
}

// ---------------- per-sequence logp sums (double) ----------------
__global__ __launch_bounds__(512) void seq_kernel(
    const float* __restrict__ tgt, const float* __restrict__ rowsum,
    const int* __restrict__ target, double* __restrict__ seqlp /* [2][8] */) {
  const int model = blockIdx.x >> 3;
  const int seq = blockIdx.x & 7;
  const int token = seq * 512 + threadIdx.x;
  int y = target[token];
  float lp = 0.f;
  if (y != IGN) lp = tgt[model * BT + token] - __logf(rowsum[model * BT + token]);
  __shared__ double sbuf[512];
  sbuf[threadIdx.x] = (double)lp;
  __syncthreads();
  for (int s = 256; s > 0; s >>= 1) {
    if (threadIdx.x < s) sbuf[threadIdx.x] += sbuf[threadIdx.x + s];
    __syncthreads();
  }
  if (threadIdx.x == 0) seqlp[model * 8 + seq] = sbuf[0];
}

// ---------------- final DPO loss ----------------
__global__ void final_kernel(const double* __restrict__ seqlp, float* __restrict__ out) {
  if (threadIdx.x == 0) {
    double loss = 0.0;
    for (int i = 0; i < 4; ++i) {
      double cp = seqlp[i], rp = seqlp[4 + i];
      double rc = seqlp[8 + i], rr = seqlp[12 + i];
      double d = 0.1 * ((cp - rc) - (rp - rr));
      double z = -d;  // -log_sigmoid(d) = softplus(-d)
      loss += fmax(z, 0.0) + log1p(exp(-fabs(z)));
    }
    out[0] = (float)(loss / 4.0);
  }
}

extern "C" void kernel_launch(void* const* d_in, const int* in_sizes, int n_in,
                              void* d_out, int out_size, void* d_ws, size_t ws_size,
                              hipStream_t stream) {
  const float* x_p = (const float*)d_in[0];
  const float* w_p = (const float*)d_in[1];
  const float* b_p = (const float*)d_in[2];
  const float* x_r = (const float*)d_in[3];
  const float* w_r = (const float*)d_in[4];
  const float* b_r = (const float*)d_in[5];
  const int* target = (const int*)d_in[6];

  char* ws = (char*)d_ws;
  size_t off = 0;
  auto take = [&](size_t bytes) {
    char* p = ws + off;
    off = (off + bytes + 255) & ~(size_t)255;
    return p;
  };
  unsigned short* Xp = (unsigned short*)take((size_t)BT * HDIM * 2);
  unsigned short* Xr = (unsigned short*)take((size_t)BT * HDIM * 2);
  unsigned short* Wp = (unsigned short*)take((size_t)VOCAB * HDIM * 2);
  unsigned short* Wr = (unsigned short*)take((size_t)VOCAB * HDIM * 2);
  float* rowsum = (float*)take(2 * BT * sizeof(float));
  float* tgt = (float*)take(2 * BT * sizeof(float));
  double* seqlp = (double*)take(16 * sizeof(double));

  hipMemsetAsync(rowsum, 0, 2 * BT * sizeof(float), stream);

  cvt_kernel<<<4096, 256, 0, stream>>>(x_p, Xp, BT * HDIM / 4);
  cvt_kernel<<<4096, 256, 0, stream>>>(x_r, Xr, BT * HDIM / 4);
  cvt_kernel<<<8192, 256, 0, stream>>>(w_p, Wp, VOCAB * HDIM / 4);
  cvt_kernel<<<8192, 256, 0, stream>>>(w_r, Wr, VOCAB * HDIM / 4);

  tgt_kernel<<<dim3(BT / 4, 2), 256, 0, stream>>>(x_p, w_p, b_p, x_r, w_r, b_r, target, tgt);

  gemm_lse_kernel<<<dim3(32 * (VOCAB / 128), 2), 256, 0, stream>>>(Xp, Wp, b_p, Xr, Wr, b_r, rowsum);

  seq_kernel<<<16, 512, 0, stream>>>(tgt, rowsum, target, seqlp);
  final_kernel<<<1, 64, 0, stream>>>(seqlp, (float*)d_out);
}